// Round 1
// baseline (221.463 us; speedup 1.0000x reference)
//
#include <hip/hip_runtime.h>

// out = x + 42.0f, elementwise over 8192*4096 fp32 (33,554,432 elems).
// Memory-bound: 268 MB total traffic, roofline ~42 us @ 6.3 TB/s.
// float4 vectorized, one thread per 4 elements.

__global__ void add42_kernel(const float4* __restrict__ x,
                             float4* __restrict__ out,
                             int n4) {
    int i = blockIdx.x * blockDim.x + threadIdx.x;
    if (i < n4) {
        float4 v = x[i];
        v.x += 42.0f;
        v.y += 42.0f;
        v.z += 42.0f;
        v.w += 42.0f;
        out[i] = v;
    }
}

extern "C" void kernel_launch(void* const* d_in, const int* in_sizes, int n_in,
                              void* d_out, int out_size, void* d_ws, size_t ws_size,
                              hipStream_t stream) {
    const float4* x = (const float4*)d_in[0];
    float4* out = (float4*)d_out;
    int n = in_sizes[0];          // 33,554,432 — divisible by 4
    int n4 = n >> 2;              // 8,388,608 float4s
    int block = 256;
    int grid = (n4 + block - 1) / block;   // 32,768 blocks
    add42_kernel<<<grid, block, 0, stream>>>(x, out, n4);
}

// Round 3
// 219.097 us; speedup vs baseline: 1.0108x; 1.0108x over previous
//
#include <hip/hip_runtime.h>

// out = x + 42.0f over 33,554,432 fp32. Memory-bound streaming kernel.
// 268 MB traffic; floor ~42.6 us @ 6.3 TB/s achievable.
// Two 16B vectors in flight per thread (MLP=2) + nontemporal hints to avoid
// L2 write-allocate pollution (stream >> 32 MB L2).
// NOTE: __builtin_nontemporal_* rejects HIP's float4 struct; use a native
// clang ext_vector_type, same 16B layout.

typedef float floatx4 __attribute__((ext_vector_type(4)));

__global__ __launch_bounds__(256) void add42_kernel(
    const floatx4* __restrict__ x, floatx4* __restrict__ out, int n4) {
    int base = blockIdx.x * (blockDim.x * 2) + threadIdx.x;
    int i0 = base;
    int i1 = base + blockDim.x;

    if (i1 < n4) {
        floatx4 a = __builtin_nontemporal_load(&x[i0]);
        floatx4 b = __builtin_nontemporal_load(&x[i1]);
        a += 42.0f;
        b += 42.0f;
        __builtin_nontemporal_store(a, &out[i0]);
        __builtin_nontemporal_store(b, &out[i1]);
    } else {
        if (i0 < n4) {
            floatx4 a = __builtin_nontemporal_load(&x[i0]);
            a += 42.0f;
            __builtin_nontemporal_store(a, &out[i0]);
        }
    }
}

extern "C" void kernel_launch(void* const* d_in, const int* in_sizes, int n_in,
                              void* d_out, int out_size, void* d_ws, size_t ws_size,
                              hipStream_t stream) {
    const floatx4* x = (const floatx4*)d_in[0];
    floatx4* out = (floatx4*)d_out;
    int n = in_sizes[0];          // 33,554,432
    int n4 = n >> 2;              // 8,388,608 16B vectors
    int block = 256;
    int per_block = block * 2;    // 512 vectors per block
    int grid = (n4 + per_block - 1) / per_block;  // 16,384 blocks
    add42_kernel<<<grid, block, 0, stream>>>(x, out, n4);
}